// Round 7
// baseline (263.573 us; speedup 1.0000x reference)
//
#include <hip/hip_runtime.h>
#include <hip/hip_bf16.h>

#define N_NODES 100000
#define N_EDGES 800000
#define IN_DIM  128
#define HIDDEN  128
#define CLASSES 40
#define CAP     32          // max degree supported (Poisson(8): P(>32) ~ 3e-11/node)
#define NSH     8           // shards == XCDs
#define SLICES  100
#define EPB     8000        // edges per slice (SLICES*EPB == N_EDGES)
#define BIN_B   (NSH*SLICES)  // 800 binning blocks: blk&7 = shard, blk>>3 = slice
#define PACK_B  24          // (4096+2048)/256
#define CAST_B  12500       // 100000*32/256
#define CUR_STRIDE 12544    // per-shard counter stride (ints, 16-aligned -> shard-pure lines)

typedef __attribute__((ext_vector_type(8))) short bf16x8;
typedef __attribute__((ext_vector_type(4))) float floatx4;
typedef __attribute__((ext_vector_type(4))) int intx4;

__device__ __forceinline__ float bf2f(unsigned short u) {
    return __uint_as_float(((unsigned int)u) << 16);
}
__device__ __forceinline__ unsigned short f2bf(float f) {
    unsigned int u = __float_as_uint(f);
    unsigned int r = 0x7fffu + ((u >> 16) & 1u);   // RNE
    return (unsigned short)((u + r) >> 16);
}
__device__ __forceinline__ int curIdx(int d) { return (d & 7) * CUR_STRIDE + (d >> 3); }

// ================= k_bin: XCD-sharded binning + weight packing (L2-clean) ==========
// Block (blk&7) bins only edges with (dst&7)==shard; blockIdx%8 round-robins onto
// XCDs -> cur/csr lines stay in ONE XCD's L2 (local atomics, merged writebacks).
// Split from the cast stream so the 77 MB stream cannot evict the binning set.
__global__ void k_bin(const int* __restrict__ src, const int* __restrict__ dst,
                      int* __restrict__ cur, int* __restrict__ csr,
                      const float* __restrict__ W1l, const float* __restrict__ W1r,
                      unsigned short* __restrict__ Bp1,
                      const float* __restrict__ W2l, const float* __restrict__ W2r,
                      unsigned short* __restrict__ Bp2) {
    int blk = blockIdx.x;
    if (blk < BIN_B) {
        int g = blk & 7;            // shard (== XCD up to constant rotation)
        int slice = blk >> 3;
        const intx4* s4p = reinterpret_cast<const intx4*>(src) + slice * (EPB / 4);
        const intx4* d4p = reinterpret_cast<const intx4*>(dst) + slice * (EPB / 4);
        for (int i = threadIdx.x; i < EPB / 4; i += 256) {
            intx4 d4 = __builtin_nontemporal_load(d4p + i);
            intx4 s4 = __builtin_nontemporal_load(s4p + i);
            #pragma unroll
            for (int j = 0; j < 4; ++j) {
                int d = d4[j];
                if ((d & 7) == g) {
                    int s = s4[j];
                    int slot = atomicAdd(&cur[g * CUR_STRIDE + (d >> 3)], 1);
                    if (slot < CAP) csr[d * CAP + slot] = s;
                }
            }
        }
    } else {
        int t = (blk - BIN_B) * 256 + threadIdx.x;
        if (t < 4096) {
            // ---- pack W1l/W1r -> Bp1[o 0..31][n 0..127][8] ----
            int o = t >> 7, n = t & 127;
            const float* W = (o < 16) ? W1l : W1r;
            int k0 = (o & 15) * 8;
            union { unsigned short us[8]; uint4 v; } pk;
            #pragma unroll
            for (int j = 0; j < 8; ++j) pk.us[j] = f2bf(W[(size_t)(k0 + j) * 128 + n]);
            *(uint4*)(Bp1 + (size_t)t * 8) = pk.v;
        } else {
            // ---- pack W2l/W2r -> Bp2[o 0..15][n 0..127][8]: n<64 W2l, n>=64 W2r ----
            int t2 = t - 4096;
            int o = t2 >> 7, n = t2 & 127;
            const float* W = (n < 64) ? W2l : W2r;
            int col = n & 63;
            int k0 = o * 8;
            union { unsigned short us[8]; uint4 v; } pk;
            #pragma unroll
            for (int j = 0; j < 8; ++j)
                pk.us[j] = (col < 40) ? f2bf(W[(size_t)(k0 + j) * 40 + col]) : (unsigned short)0;
            *(uint4*)(Bp2 + (size_t)t2 * 8) = pk.v;
        }
    }
}

// ================= k_cast: x f32 -> bf16 into DENSE Xbf[n][128] ==================
__global__ void k_cast(const float* __restrict__ x, unsigned short* __restrict__ Xbf) {
    int t = blockIdx.x * 256 + threadIdx.x;
    int n = t >> 5, g = t & 31;
    float4 v = reinterpret_cast<const float4*>(x + (size_t)n * 128)[g];
    ushort4 u = { f2bf(v.x), f2bf(v.y), f2bf(v.z), f2bf(v.w) };
    *(ushort4*)(Xbf + (size_t)n * 128 + g * 4) = u;
}

// ================= gather-mean layer 1: 1 node/wave, dense Xbf table ===============
// 8-slot blocks (2 loads in flight, 16 adds/lane for the typical deg-8 node --
// half the old VALU). shfl HOISTED out of the divergent branch.
__global__ void k_agg1(const unsigned short* __restrict__ Xbf,
                       unsigned short* __restrict__ Mean,
                       const int* __restrict__ deg, const int* __restrict__ csr) {
    int n = blockIdx.x * 4 + (threadIdx.x >> 6);
    int lane = threadIdx.x & 63;
    if (n >= N_NODES) return;
    int cnt = min(deg[curIdx(n)], CAP);
    int nl = csr[n * CAP + (lane & (CAP - 1))];   // lanes 32..63 mirror 0..31
    int r = lane >> 4, c = lane & 15;
    float acc[8] = {0.f, 0.f, 0.f, 0.f, 0.f, 0.f, 0.f, 0.f};
    for (int base = 0; base < cnt; base += 8) {
        #pragma unroll
        for (int u = 0; u < 2; ++u) {
            int e = base + u * 4 + r;
            int s = __shfl(nl, min(e, cnt - 1) & 31, 64);   // whole wave active here
            bf16x8 v = {};
            if (e < cnt)
                v = *(const bf16x8*)(Xbf + (size_t)s * 128 + c * 8);
            #pragma unroll
            for (int j = 0; j < 8; ++j) acc[j] += bf2f((unsigned short)v[j]);
        }
    }
    #pragma unroll
    for (int j = 0; j < 8; ++j) {
        acc[j] += __shfl_xor(acc[j], 16, 64);
        acc[j] += __shfl_xor(acc[j], 32, 64);
    }
    if (lane < 16) {
        float inv = 1.0f / fmaxf((float)cnt, 1.0f);
        union { unsigned short us[8]; bf16x8 v; } pk;
        #pragma unroll
        for (int j = 0; j < 8; ++j) pk.us[j] = f2bf(acc[j] * inv);
        *(bf16x8*)(Mean + (size_t)n * 128 + c * 8) = pk.v;
    }
}

// ================= fused MFMA: h=relu([mean|x]@Wp1+b1); P|R = h@Wp2 =================
__global__ __launch_bounds__(256)
void k_gemm(const unsigned short* __restrict__ Mean, const unsigned short* __restrict__ Xbf,
            unsigned short* __restrict__ Pbuf, float* __restrict__ Rbuf,
            const unsigned short* __restrict__ Bp1, const float* __restrict__ b1,
            const unsigned short* __restrict__ Bp2) {
    __shared__ unsigned short Hs[4][16][136];
    int wv = threadIdx.x >> 6, lane = threadIdx.x & 63;
    int q = lane >> 4, nn = lane & 15;
    int m0 = blockIdx.x * 64 + wv * 16;
    int ma = m0 + nn;
    bool mv = (ma < N_NODES);

    // phase A: [mean|x] @ Bp1, K=256 (kt<4 mean rows, kt>=4 x rows)
    floatx4 acc[8] = {};
    for (int kt = 0; kt < 8; ++kt) {
        bf16x8 a = {};
        if (mv) {
            const unsigned short* arow = (kt < 4) ? (Mean + (size_t)ma * 128 + kt * 32)
                                                  : (Xbf  + (size_t)ma * 128 + (kt - 4) * 32);
            a = *(const bf16x8*)(arow + q * 8);
        }
        bf16x8 b[8];
        #pragma unroll
        for (int nt = 0; nt < 8; ++nt)
            b[nt] = *(const bf16x8*)(Bp1 + ((size_t)((kt * 4 + q) * 128 + nt * 16 + nn)) * 8);
        #pragma unroll
        for (int nt = 0; nt < 8; ++nt)
            acc[nt] = __builtin_amdgcn_mfma_f32_16x16x32_bf16(a, b[nt], acc[nt], 0, 0, 0);
    }
    // epilogue A: relu + bias -> LDS (wave-local tile; per-wave DS ops are in-order)
    #pragma unroll
    for (int nt = 0; nt < 8; ++nt) {
        int col = nt * 16 + nn;
        float bias = b1[col];
        #pragma unroll
        for (int r = 0; r < 4; ++r)
            Hs[wv][q * 4 + r][col] = f2bf(fmaxf(acc[nt][r] + bias, 0.f));
    }
    // phase B: h @ Bp2, K=128 -> P (cols 0..63) | R (cols 64..127)
    floatx4 acc2[8] = {};
    for (int kt = 0; kt < 4; ++kt) {
        bf16x8 a = *(const bf16x8*)(&Hs[wv][nn][kt * 32 + q * 8]);
        bf16x8 b[8];
        #pragma unroll
        for (int nt = 0; nt < 8; ++nt)
            b[nt] = *(const bf16x8*)(Bp2 + ((size_t)((kt * 4 + q) * 128 + nt * 16 + nn)) * 8);
        #pragma unroll
        for (int nt = 0; nt < 8; ++nt)
            acc2[nt] = __builtin_amdgcn_mfma_f32_16x16x32_bf16(a, b[nt], acc2[nt], 0, 0, 0);
    }
    // epilogue B: P bf16 -> dense Pbuf[n][64]; R f32 -> dense Rbuf[n][64]
    #pragma unroll
    for (int nt = 0; nt < 4; ++nt) {
        int col = nt * 16 + nn;
        #pragma unroll
        for (int r = 0; r < 4; ++r) {
            int ro = m0 + q * 4 + r;
            if (ro < N_NODES)
                Pbuf[(size_t)ro * 64 + col] = f2bf(acc2[nt][r]);
        }
    }
    #pragma unroll
    for (int nt = 4; nt < 8; ++nt) {
        int col = (nt - 4) * 16 + nn;
        #pragma unroll
        for (int r = 0; r < 4; ++r) {
            int ro = m0 + q * 4 + r;
            if (ro < N_NODES)
                Rbuf[(size_t)ro * 64 + col] = acc2[nt][r];
        }
    }
}

// ========== gather-mean layer 2: 1 node/wave, dense Pbuf (12.8 MB, L3-hot) =========
__global__ void k_agg2(const unsigned short* __restrict__ Pbuf, const float* __restrict__ Rbuf,
                       const int* __restrict__ deg, const int* __restrict__ csr,
                       const float* __restrict__ b2, float* __restrict__ out) {
    int n = blockIdx.x * 4 + (threadIdx.x >> 6);
    int lane = threadIdx.x & 63;
    if (n >= N_NODES) return;
    int cnt = min(deg[curIdx(n)], CAP);
    int nl = csr[n * CAP + (lane & (CAP - 1))];   // lanes 32..63 mirror 0..31
    int r = lane >> 3, c = lane & 7;
    float acc[8] = {0.f, 0.f, 0.f, 0.f, 0.f, 0.f, 0.f, 0.f};
    for (int base = 0; base < cnt; base += 8) {
        int e = base + r;
        int s = __shfl(nl, min(e, cnt - 1) & 31, 64);   // whole wave active here
        bf16x8 v = {};
        if (e < cnt)
            v = *(const bf16x8*)(Pbuf + (size_t)s * 64 + c * 8);
        #pragma unroll
        for (int j = 0; j < 8; ++j) acc[j] += bf2f((unsigned short)v[j]);
    }
    #pragma unroll
    for (int j = 0; j < 8; ++j) {
        acc[j] += __shfl_xor(acc[j], 8, 64);
        acc[j] += __shfl_xor(acc[j], 16, 64);
        acc[j] += __shfl_xor(acc[j], 32, 64);
    }
    if (lane < 5) {   // cols c*8..c*8+7, all < 40
        float inv = 1.0f / fmaxf((float)cnt, 1.0f);
        const float* Rrow = Rbuf + (size_t)n * 64;
        float o[8];
        #pragma unroll
        for (int j = 0; j < 8; ++j)
            o[j] = acc[j] * inv + Rrow[c * 8 + j] + b2[c * 8 + j];
        float* op = out + (size_t)n * CLASSES + c * 8;
        *(float4*)(op)     = make_float4(o[0], o[1], o[2], o[3]);
        *(float4*)(op + 4) = make_float4(o[4], o[5], o[6], o[7]);
    }
}

extern "C" void kernel_launch(void* const* d_in, const int* in_sizes, int n_in,
                              void* d_out, int out_size, void* d_ws, size_t ws_size,
                              hipStream_t stream) {
    const float* x   = (const float*)d_in[0];
    const int*   ei  = (const int*)d_in[1];
    const float* W1l = (const float*)d_in[2];
    const float* W1r = (const float*)d_in[3];
    const float* b1  = (const float*)d_in[4];
    const float* W2l = (const float*)d_in[5];
    const float* W2r = (const float*)d_in[6];
    const float* b2  = (const float*)d_in[7];
    float* out = (float*)d_out;

    const int* src = ei;
    const int* dst = ei + N_EDGES;

    char* ws = (char*)d_ws;
    size_t off = 0;
    auto alloc = [&](size_t bytes) { void* p = ws + off; off += (bytes + 511) & ~(size_t)511; return p; };
    int* cur = (int*)alloc((size_t)NSH * CUR_STRIDE * 4);              // sharded degree/cursor
    int* csr = (int*)alloc((size_t)N_NODES * CAP * 4);                 // padded CSR (12.8 MB)
    unsigned short* Bp1 = (unsigned short*)alloc((size_t)32 * 128 * 8 * 2);
    unsigned short* Bp2 = (unsigned short*)alloc((size_t)16 * 128 * 8 * 2);
    unsigned short* Xbf  = (unsigned short*)alloc((size_t)N_NODES * 128 * 2);  // dense x bf16
    unsigned short* Mean = (unsigned short*)alloc((size_t)N_NODES * 128 * 2);  // dense means
    unsigned short* Pbuf = (unsigned short*)alloc((size_t)N_NODES * 64 * 2);   // dense P bf16
    float* Rbuf = (float*)alloc((size_t)N_NODES * 64 * 4);                     // dense R f32

    hipMemsetAsync(cur, 0, (size_t)NSH * CUR_STRIDE * 4, stream);

    k_bin<<<BIN_B + PACK_B, 256, 0, stream>>>(src, dst, cur, csr,
                                              W1l, W1r, Bp1, W2l, W2r, Bp2);
    k_cast<<<CAST_B, 256, 0, stream>>>(x, Xbf);

    k_agg1<<<(N_NODES + 3) / 4, 256, 0, stream>>>(Xbf, Mean, cur, csr);
    k_gemm<<<(N_NODES + 63) / 64, 256, 0, stream>>>(Mean, Xbf, Pbuf, Rbuf, Bp1, b1, Bp2);
    k_agg2<<<(N_NODES + 3) / 4, 256, 0, stream>>>(Pbuf, Rbuf, cur, csr, b2, out);
}

// Round 8
// 248.538 us; speedup vs baseline: 1.0605x; 1.0605x over previous
//
#include <hip/hip_runtime.h>
#include <hip/hip_bf16.h>

#define N_NODES 100000
#define N_EDGES 800000
#define IN_DIM  128
#define HIDDEN  128
#define CLASSES 40
#define CAP     32          // max degree supported (Poisson(8): P(>32) ~ 3e-11/node)
#define NSH     8           // shards == XCDs
#define SLICES  100
#define EPB     8000        // edges per slice (SLICES*EPB == N_EDGES)
#define BIN_B   (NSH*SLICES)  // 800 binning blocks: blk&7 = shard, blk>>3 = slice
#define CAST_B  12500       // 100000*32/256
#define PACK_B  24          // (4096+2048)/256
#define CUR_STRIDE 12544    // per-shard counter stride (ints, 16-aligned -> shard-pure lines)

typedef __attribute__((ext_vector_type(8))) short bf16x8;
typedef __attribute__((ext_vector_type(4))) float floatx4;

__device__ __forceinline__ float bf2f(unsigned short u) {
    return __uint_as_float(((unsigned int)u) << 16);
}
__device__ __forceinline__ unsigned short f2bf(float f) {
    unsigned int u = __float_as_uint(f);
    unsigned int r = 0x7fffu + ((u >> 16) & 1u);   // RNE
    return (unsigned short)((u + r) >> 16);
}
__device__ __forceinline__ int curIdx(int d) { return (d & 7) * CUR_STRIDE + (d >> 3); }

// ================= prep: bin + cast_x + pack1 + pack2 in ONE launch ================
// r7 evidence: k_bin ALONE = 45.5 us (L2-atomic-throughput floor: 800K atomics / 8
// XCD-L2s @ ~1/cy ~= 42 us) and cast ~13 us -- serial split = 58.5. Combined (r2
// measured 47-50) the BW-bound cast stream HIDES the atomic-bound binning. So:
// recombined, exact r2 form (no NT hints -- r6's NT was neutral-to-worse).
// Binning is XCD-sharded: block (blk&7) bins only edges with (dst&7)==shard;
// blockIdx%8 round-robins onto XCDs -> cur/csr lines stay in ONE XCD's L2.
__global__ void k_prep(const int* __restrict__ src, const int* __restrict__ dst,
                       int* __restrict__ cur, int* __restrict__ csr,
                       const float* __restrict__ x, unsigned short* __restrict__ Xbf,
                       const float* __restrict__ W1l, const float* __restrict__ W1r,
                       unsigned short* __restrict__ Bp1,
                       const float* __restrict__ W2l, const float* __restrict__ W2r,
                       unsigned short* __restrict__ Bp2) {
    int blk = blockIdx.x;
    if (blk < BIN_B) {
        int g = blk & 7;            // shard (== XCD up to constant rotation)
        int slice = blk >> 3;
        const int4* s4p = reinterpret_cast<const int4*>(src) + slice * (EPB / 4);
        const int4* d4p = reinterpret_cast<const int4*>(dst) + slice * (EPB / 4);
        for (int i = threadIdx.x; i < EPB / 4; i += 256) {
            int4 d4 = d4p[i];
            int4 s4 = s4p[i];
            #pragma unroll
            for (int j = 0; j < 4; ++j) {
                int d = (&d4.x)[j];
                if ((d & 7) == g) {
                    int s = (&s4.x)[j];
                    int slot = atomicAdd(&cur[g * CUR_STRIDE + (d >> 3)], 1);
                    if (slot < CAP) csr[d * CAP + slot] = s;
                }
            }
        }
    } else if (blk < BIN_B + CAST_B) {
        // ---- x f32 -> bf16 into DENSE Xbf[n][128] ----
        int t = (blk - BIN_B) * 256 + threadIdx.x;
        int n = t >> 5, g = t & 31;
        float4 v = reinterpret_cast<const float4*>(x + (size_t)n * 128)[g];
        ushort4 u = { f2bf(v.x), f2bf(v.y), f2bf(v.z), f2bf(v.w) };
        *(ushort4*)(Xbf + (size_t)n * 128 + g * 4) = u;
    } else {
        int t = (blk - BIN_B - CAST_B) * 256 + threadIdx.x;
        if (t < 4096) {
            // ---- pack W1l/W1r -> Bp1[o 0..31][n 0..127][8] ----
            int o = t >> 7, n = t & 127;
            const float* W = (o < 16) ? W1l : W1r;
            int k0 = (o & 15) * 8;
            union { unsigned short us[8]; uint4 v; } pk;
            #pragma unroll
            for (int j = 0; j < 8; ++j) pk.us[j] = f2bf(W[(size_t)(k0 + j) * 128 + n]);
            *(uint4*)(Bp1 + (size_t)t * 8) = pk.v;
        } else {
            // ---- pack W2l/W2r -> Bp2[o 0..15][n 0..127][8]: n<64 W2l, n>=64 W2r ----
            int t2 = t - 4096;
            int o = t2 >> 7, n = t2 & 127;
            const float* W = (n < 64) ? W2l : W2r;
            int col = n & 63;
            int k0 = o * 8;
            union { unsigned short us[8]; uint4 v; } pk;
            #pragma unroll
            for (int j = 0; j < 8; ++j)
                pk.us[j] = (col < 40) ? f2bf(W[(size_t)(k0 + j) * 40 + col]) : (unsigned short)0;
            *(uint4*)(Bp2 + (size_t)t2 * 8) = pk.v;
        }
    }
}

// ================= gather-mean layer 1: 1 node/wave (TLP-max), dense Xbf ===========
// At the random-line service floor (r7: FETCH == logical 102 MB, ~2.7 TB/s);
// structure frozen. shfl HOISTED out of the divergent branch.
__global__ void k_agg1(const unsigned short* __restrict__ Xbf,
                       unsigned short* __restrict__ Mean,
                       const int* __restrict__ deg, const int* __restrict__ csr) {
    int n = blockIdx.x * 4 + (threadIdx.x >> 6);
    int lane = threadIdx.x & 63;
    if (n >= N_NODES) return;
    int cnt = min(deg[curIdx(n)], CAP);
    int nl = csr[n * CAP + (lane & (CAP - 1))];   // lanes 32..63 mirror 0..31
    int r = lane >> 4, c = lane & 15;
    float acc[8] = {0.f, 0.f, 0.f, 0.f, 0.f, 0.f, 0.f, 0.f};
    for (int base = 0; base < cnt; base += 8) {
        #pragma unroll
        for (int u = 0; u < 2; ++u) {
            int e = base + u * 4 + r;
            int s = __shfl(nl, min(e, cnt - 1) & 31, 64);   // whole wave active here
            bf16x8 v = {};
            if (e < cnt)
                v = *(const bf16x8*)(Xbf + (size_t)s * 128 + c * 8);
            #pragma unroll
            for (int j = 0; j < 8; ++j) acc[j] += bf2f((unsigned short)v[j]);
        }
    }
    #pragma unroll
    for (int j = 0; j < 8; ++j) {
        acc[j] += __shfl_xor(acc[j], 16, 64);
        acc[j] += __shfl_xor(acc[j], 32, 64);
    }
    if (lane < 16) {
        float inv = 1.0f / fmaxf((float)cnt, 1.0f);
        union { unsigned short us[8]; bf16x8 v; } pk;
        #pragma unroll
        for (int j = 0; j < 8; ++j) pk.us[j] = f2bf(acc[j] * inv);
        *(bf16x8*)(Mean + (size_t)n * 128 + c * 8) = pk.v;
    }
}

// ================= fused MFMA: h=relu([mean|x]@Wp1+b1); P|R = h@Wp2 =================
// R now stored bf16 (halves R write: 25.6 -> 12.8 MB; err ~2^-9 rel on R~N(0,1.2)).
__global__ __launch_bounds__(256)
void k_gemm(const unsigned short* __restrict__ Mean, const unsigned short* __restrict__ Xbf,
            unsigned short* __restrict__ Pbuf, unsigned short* __restrict__ Rbuf,
            const unsigned short* __restrict__ Bp1, const float* __restrict__ b1,
            const unsigned short* __restrict__ Bp2) {
    __shared__ unsigned short Hs[4][16][136];
    int wv = threadIdx.x >> 6, lane = threadIdx.x & 63;
    int q = lane >> 4, nn = lane & 15;
    int m0 = blockIdx.x * 64 + wv * 16;
    int ma = m0 + nn;
    bool mv = (ma < N_NODES);

    // phase A: [mean|x] @ Bp1, K=256 (kt<4 mean rows, kt>=4 x rows)
    floatx4 acc[8] = {};
    for (int kt = 0; kt < 8; ++kt) {
        bf16x8 a = {};
        if (mv) {
            const unsigned short* arow = (kt < 4) ? (Mean + (size_t)ma * 128 + kt * 32)
                                                  : (Xbf  + (size_t)ma * 128 + (kt - 4) * 32);
            a = *(const bf16x8*)(arow + q * 8);
        }
        bf16x8 b[8];
        #pragma unroll
        for (int nt = 0; nt < 8; ++nt)
            b[nt] = *(const bf16x8*)(Bp1 + ((size_t)((kt * 4 + q) * 128 + nt * 16 + nn)) * 8);
        #pragma unroll
        for (int nt = 0; nt < 8; ++nt)
            acc[nt] = __builtin_amdgcn_mfma_f32_16x16x32_bf16(a, b[nt], acc[nt], 0, 0, 0);
    }
    // epilogue A: relu + bias -> LDS (wave-local tile; per-wave DS ops are in-order)
    #pragma unroll
    for (int nt = 0; nt < 8; ++nt) {
        int col = nt * 16 + nn;
        float bias = b1[col];
        #pragma unroll
        for (int r = 0; r < 4; ++r)
            Hs[wv][q * 4 + r][col] = f2bf(fmaxf(acc[nt][r] + bias, 0.f));
    }
    // phase B: h @ Bp2, K=128 -> P (cols 0..63) | R (cols 64..127)
    floatx4 acc2[8] = {};
    for (int kt = 0; kt < 4; ++kt) {
        bf16x8 a = *(const bf16x8*)(&Hs[wv][nn][kt * 32 + q * 8]);
        bf16x8 b[8];
        #pragma unroll
        for (int nt = 0; nt < 8; ++nt)
            b[nt] = *(const bf16x8*)(Bp2 + ((size_t)((kt * 4 + q) * 128 + nt * 16 + nn)) * 8);
        #pragma unroll
        for (int nt = 0; nt < 8; ++nt)
            acc2[nt] = __builtin_amdgcn_mfma_f32_16x16x32_bf16(a, b[nt], acc2[nt], 0, 0, 0);
    }
    // epilogue B: P bf16 -> dense Pbuf[n][64]; R bf16 -> dense Rbuf[n][64]
    #pragma unroll
    for (int nt = 0; nt < 4; ++nt) {
        int col = nt * 16 + nn;
        #pragma unroll
        for (int r = 0; r < 4; ++r) {
            int ro = m0 + q * 4 + r;
            if (ro < N_NODES)
                Pbuf[(size_t)ro * 64 + col] = f2bf(acc2[nt][r]);
        }
    }
    #pragma unroll
    for (int nt = 4; nt < 8; ++nt) {
        int col = (nt - 4) * 16 + nn;
        #pragma unroll
        for (int r = 0; r < 4; ++r) {
            int ro = m0 + q * 4 + r;
            if (ro < N_NODES)
                Rbuf[(size_t)ro * 64 + col] = f2bf(acc2[nt][r]);
        }
    }
}

// ========== gather-mean layer 2: 1 node/wave, dense Pbuf (12.8 MB) + bf16 R =========
__global__ void k_agg2(const unsigned short* __restrict__ Pbuf,
                       const unsigned short* __restrict__ Rbuf,
                       const int* __restrict__ deg, const int* __restrict__ csr,
                       const float* __restrict__ b2, float* __restrict__ out) {
    int n = blockIdx.x * 4 + (threadIdx.x >> 6);
    int lane = threadIdx.x & 63;
    if (n >= N_NODES) return;
    int cnt = min(deg[curIdx(n)], CAP);
    int nl = csr[n * CAP + (lane & (CAP - 1))];   // lanes 32..63 mirror 0..31
    int r = lane >> 3, c = lane & 7;
    float acc[8] = {0.f, 0.f, 0.f, 0.f, 0.f, 0.f, 0.f, 0.f};
    for (int base = 0; base < cnt; base += 8) {
        int e = base + r;
        int s = __shfl(nl, min(e, cnt - 1) & 31, 64);   // whole wave active here
        bf16x8 v = {};
        if (e < cnt)
            v = *(const bf16x8*)(Pbuf + (size_t)s * 64 + c * 8);
        #pragma unroll
        for (int j = 0; j < 8; ++j) acc[j] += bf2f((unsigned short)v[j]);
    }
    #pragma unroll
    for (int j = 0; j < 8; ++j) {
        acc[j] += __shfl_xor(acc[j], 8, 64);
        acc[j] += __shfl_xor(acc[j], 16, 64);
        acc[j] += __shfl_xor(acc[j], 32, 64);
    }
    if (lane < 5) {   // cols c*8..c*8+7, all < 40
        float inv = 1.0f / fmaxf((float)cnt, 1.0f);
        bf16x8 rv = *(const bf16x8*)(Rbuf + (size_t)n * 64 + c * 8);
        float o[8];
        #pragma unroll
        for (int j = 0; j < 8; ++j)
            o[j] = acc[j] * inv + bf2f((unsigned short)rv[j]) + b2[c * 8 + j];
        float* op = out + (size_t)n * CLASSES + c * 8;
        *(float4*)(op)     = make_float4(o[0], o[1], o[2], o[3]);
        *(float4*)(op + 4) = make_float4(o[4], o[5], o[6], o[7]);
    }
}

extern "C" void kernel_launch(void* const* d_in, const int* in_sizes, int n_in,
                              void* d_out, int out_size, void* d_ws, size_t ws_size,
                              hipStream_t stream) {
    const float* x   = (const float*)d_in[0];
    const int*   ei  = (const int*)d_in[1];
    const float* W1l = (const float*)d_in[2];
    const float* W1r = (const float*)d_in[3];
    const float* b1  = (const float*)d_in[4];
    const float* W2l = (const float*)d_in[5];
    const float* W2r = (const float*)d_in[6];
    const float* b2  = (const float*)d_in[7];
    float* out = (float*)d_out;

    const int* src = ei;
    const int* dst = ei + N_EDGES;

    char* ws = (char*)d_ws;
    size_t off = 0;
    auto alloc = [&](size_t bytes) { void* p = ws + off; off += (bytes + 511) & ~(size_t)511; return p; };
    int* cur = (int*)alloc((size_t)NSH * CUR_STRIDE * 4);              // sharded degree/cursor
    int* csr = (int*)alloc((size_t)N_NODES * CAP * 4);                 // padded CSR (12.8 MB)
    unsigned short* Bp1 = (unsigned short*)alloc((size_t)32 * 128 * 8 * 2);
    unsigned short* Bp2 = (unsigned short*)alloc((size_t)16 * 128 * 8 * 2);
    unsigned short* Xbf  = (unsigned short*)alloc((size_t)N_NODES * 128 * 2);  // dense x bf16
    unsigned short* Mean = (unsigned short*)alloc((size_t)N_NODES * 128 * 2);  // dense means
    unsigned short* Pbuf = (unsigned short*)alloc((size_t)N_NODES * 64 * 2);   // dense P bf16
    unsigned short* Rbuf = (unsigned short*)alloc((size_t)N_NODES * 64 * 2);   // dense R bf16

    hipMemsetAsync(cur, 0, (size_t)NSH * CUR_STRIDE * 4, stream);

    k_prep<<<BIN_B + CAST_B + PACK_B, 256, 0, stream>>>(
        src, dst, cur, csr, x, Xbf, W1l, W1r, Bp1, W2l, W2r, Bp2);

    k_agg1<<<(N_NODES + 3) / 4, 256, 0, stream>>>(Xbf, Mean, cur, csr);
    k_gemm<<<(N_NODES + 63) / 64, 256, 0, stream>>>(Mean, Xbf, Pbuf, Rbuf, Bp1, b1, Bp2);
    k_agg2<<<(N_NODES + 3) / 4, 256, 0, stream>>>(Pbuf, Rbuf, cur, csr, b2, out);
}